// Round 4
// baseline (366.559 us; speedup 1.0000x reference)
//
#include <hip/hip_runtime.h>

typedef _Float16 half2v __attribute__((ext_vector_type(2)));

#define LOG2E 1.44269504088896340736f
#define LN2   0.69314718055994530942f

static __device__ __forceinline__ float fdot2(half2v a, half2v b, float c) {
#if __has_builtin(__builtin_amdgcn_fdot2)
    return __builtin_amdgcn_fdot2(a, b, c, false);
#else
    return fmaf((float)a.y, (float)b.y, fmaf((float)a.x, (float)b.x, c));
#endif
}

static __device__ __forceinline__ half2v bch(unsigned u) {
    return __builtin_bit_cast(half2v, u);
}

// s_j = sum_i a[i]*Texp[i][j]; alpha is f16[64] in LDS (8 broadcast b128 reads).
// 8 accumulators => dep chain of 4 fdot2 each.
static __device__ __forceinline__ float dot64(const _Float16* a_sh,
                                              const half2v (&th)[32]) {
    const uint4* pa = (const uint4*)a_sh;
    uint4 q0 = pa[0], q1 = pa[1], q2 = pa[2], q3 = pa[3];
    uint4 q4 = pa[4], q5 = pa[5], q6 = pa[6], q7 = pa[7];
    float a0 = 0.f, a1 = 0.f, a2 = 0.f, a3 = 0.f;
    float a4 = 0.f, a5 = 0.f, a6 = 0.f, a7 = 0.f;
    a0 = fdot2(bch(q0.x), th[ 0], a0);  a1 = fdot2(bch(q0.y), th[ 1], a1);
    a2 = fdot2(bch(q0.z), th[ 2], a2);  a3 = fdot2(bch(q0.w), th[ 3], a3);
    a4 = fdot2(bch(q1.x), th[ 4], a4);  a5 = fdot2(bch(q1.y), th[ 5], a5);
    a6 = fdot2(bch(q1.z), th[ 6], a6);  a7 = fdot2(bch(q1.w), th[ 7], a7);
    a0 = fdot2(bch(q2.x), th[ 8], a0);  a1 = fdot2(bch(q2.y), th[ 9], a1);
    a2 = fdot2(bch(q2.z), th[10], a2);  a3 = fdot2(bch(q2.w), th[11], a3);
    a4 = fdot2(bch(q3.x), th[12], a4);  a5 = fdot2(bch(q3.y), th[13], a5);
    a6 = fdot2(bch(q3.z), th[14], a6);  a7 = fdot2(bch(q3.w), th[15], a7);
    a0 = fdot2(bch(q4.x), th[16], a0);  a1 = fdot2(bch(q4.y), th[17], a1);
    a2 = fdot2(bch(q4.z), th[18], a2);  a3 = fdot2(bch(q4.w), th[19], a3);
    a4 = fdot2(bch(q5.x), th[20], a4);  a5 = fdot2(bch(q5.y), th[21], a5);
    a6 = fdot2(bch(q5.z), th[22], a6);  a7 = fdot2(bch(q5.w), th[23], a7);
    a0 = fdot2(bch(q6.x), th[24], a0);  a1 = fdot2(bch(q6.y), th[25], a1);
    a2 = fdot2(bch(q6.z), th[26], a2);  a3 = fdot2(bch(q6.w), th[27], a3);
    a4 = fdot2(bch(q7.x), th[28], a4);  a5 = fdot2(bch(q7.y), th[29], a5);
    a6 = fdot2(bch(q7.z), th[30], a6);  a7 = fdot2(bch(q7.w), th[31], a7);
    return ((a0 + a1) + (a2 + a3)) + ((a4 + a5) + (a6 + a7));
}

// B=256, T=1024, K=64. One wave per batch; lane j owns state j.
// Exp-domain forward recursion with per-step 2^-7 fold + exact pow2
// re-centering each chunk. No barriers in the loop (single wave => DS pipe
// in-order). __launch_bounds__(64,1): unlock full VGPR budget so the
// next-chunk prefetch stays register-resident (at (64) default the allocator
// targeted 48 VGPRs and sank the prefetch loads to their use site).
__global__ __launch_bounds__(64, 1) void crf_fwd(
    const int*   __restrict__ yg,   // (B,T) int32
    const float* __restrict__ em,   // (B,T,K) fp32
    const float* __restrict__ tr,   // (K,K) fp32
    float*       __restrict__ out)  // scalar
{
    constexpr int T = 1024, K = 64;
    const int b = blockIdx.x;
    const int j = threadIdx.x;

    __shared__ _Float16 a_sh[K] __attribute__((aligned(16)));

    // lane j holds column j of exp(trans) packed as 32 half2
    half2v th[32];
#pragma unroll
    for (int i = 0; i < 32; ++i) {
        half2v h;
        h.x = (_Float16)exp2f(tr[(2 * i) * K + j] * LOG2E);
        h.y = (_Float16)exp2f(tr[(2 * i + 1) * K + j] * LOG2E);
        th[i] = h;
    }

    const float* emb = em + (size_t)b * T * K;
    const int*   yb  = yg + b * T;

    // ---- t = 0: alpha0 = emissions[:,0,:], centered on its max ----
    const float e0 = emb[j];
    float M0 = e0;
#pragma unroll
    for (int o = 32; o > 0; o >>= 1) M0 = fmaxf(M0, __shfl_xor(M0, o, 64));
    float a = exp2f((e0 - M0) * LOG2E);   // max = 1
    float L = M0;                         // alpha_j = L + log(a_j)

    const int y0 = yb[0];
    float e_part = (y0 != 0 && j == y0) ? e0 : 0.0f;
    float t_part = 0.0f;
    int   nupd   = 0;
    int   yprev  = y0;

    a_sh[j] = (_Float16)a;

    // ---- prefetch t = 1..8 ----
    float ld[8]; int yv[8];
#pragma unroll
    for (int u = 0; u < 8; ++u) { ld[u] = emb[(1 + u) * K + j]; yv[u] = yb[1 + u]; }

    // ---- main loop: 127 chunks of 8 steps (t = 1..1016) ----
    for (int tb = 1; tb <= T - 15; tb += 8) {
        // chunk top: capture labels, masks, transition gathers (small bubble)
        int yc[8]; bool up[8]; float tvv[8];
        {
            int yp = yprev;
#pragma unroll
            for (int u = 0; u < 8; ++u) {
                const int yt = yv[u];
                yc[u]  = yt;
                up[u]  = (yt != 0);
                tvv[u] = tr[yp * K + yt];   // L1-resident 16 KB table
                yp = yt;
            }
            yprev = yp;
        }

        // ---- 8 serial steps; next-chunk prefetch hidden in the read shadow
        float raw[8];
#pragma unroll
        for (int u = 0; u < 8; ++u) {
            // issue LDS reads first (serial-critical path)
            const float s = dot64(a_sh, th);
            // these execute in the LDS-read shadow:
            const float f  = ld[u];
            raw[u] = f;
            const float ex = exp2f(f * LOG2E - 7.0f);     // exp(em)*2^-7
            {
                int tn = tb + 8 + u; tn = (tn > T - 1) ? (T - 1) : tn;
                ld[u] = emb[tn * K + j];                   // prefetch chunk+1
                yv[u] = yb[tn];
            }
            const float an = s * ex;
            a = up[u] ? an : a;
            a_sh[j] = (_Float16)fminf(a, 60000.0f);        // clamp: no f16 inf
        }

        // ---- off-path bookkeeping ----
#pragma unroll
        for (int u = 0; u < 8; ++u) {
            if (up[u]) {
                t_part += tvv[u];
                nupd   += 1;
                if (j == yc[u]) e_part += raw[u];
            }
        }

        // ---- chunk-end re-centering by exact power of two (wave-uniform) ----
        unsigned ab = (unsigned)__builtin_amdgcn_readlane((int)__float_as_uint(a), 0);
        int ef = (int)((ab >> 23) & 0xFF);
        if (ef > 0 && ef < 255 && ef != 127) {
            const int E = ef - 127;
            const float sc = __uint_as_float((unsigned)(127 - E) << 23); // 2^-E
            a *= sc;
            L += (float)E * LN2;
            a_sh[j] = (_Float16)fminf(a, 60000.0f);
        }
    }

    // ---- tail: t = 1017..1023 (ld[0..6]/yv[0..6] hold them) ----
#pragma unroll
    for (int u = 0; u < 7; ++u) {
        const int yt   = yv[u];
        const bool upd = (yt != 0);
        const float tv = tr[yprev * K + yt];
        const float ex = exp2f(ld[u] * LOG2E - 7.0f);
        const float s  = dot64(a_sh, th);
        const float an = s * ex;
        if (upd) {
            t_part += tv;
            nupd   += 1;
            if (j == yt) e_part += ld[u];
        }
        a = upd ? an : a;
        a_sh[j] = (_Float16)fminf(a, 60000.0f);
        yprev = yt;
    }

    L += 7.0f * LN2 * (float)nupd;   // fold the per-update 2^-7 scales

    // ---- finalize: log_z = L + log(sum_j a_j) ----
    float asum = a, esum = e_part;
#pragma unroll
    for (int o = 32; o > 0; o >>= 1) {
        asum += __shfl_xor(asum, o, 64);
        esum += __shfl_xor(esum, o, 64);
    }
    const float logz = L + __log2f(asum) * LN2;

    if (j == 0) {
        const float ll = esum + t_part - logz;
        atomicAdd(out, ll * (-1.0f / 256.0f));  // -mean over B
    }
}

extern "C" void kernel_launch(void* const* d_in, const int* in_sizes, int n_in,
                              void* d_out, int out_size, void* d_ws, size_t ws_size,
                              hipStream_t stream) {
    const int*   y  = (const int*)d_in[0];
    const float* em = (const float*)d_in[1];
    const float* tr = (const float*)d_in[2];
    float* out = (float*)d_out;

    hipMemsetAsync(out, 0, sizeof(float), stream);
    crf_fwd<<<dim3(256), dim3(64), 0, stream>>>(y, em, tr, out);
}

// Round 5
// 288.601 us; speedup vs baseline: 1.2701x; 1.2701x over previous
//
#include <hip/hip_runtime.h>

typedef _Float16 half2v __attribute__((ext_vector_type(2)));

#define LOG2E 1.44269504088896340736f
#define LN2   0.69314718055994530942f

static __device__ __forceinline__ float fdot2(half2v a, half2v b, float c) {
#if __has_builtin(__builtin_amdgcn_fdot2)
    return __builtin_amdgcn_fdot2(a, b, c, false);
#else
    return fmaf((float)a.y, (float)b.y, fmaf((float)a.x, (float)b.x, c));
#endif
}

static __device__ __forceinline__ half2v bch(unsigned u) {
    return __builtin_bit_cast(half2v, u);
}

// s_j = sum_i a[i]*Texp[i][j]; alpha is f16[64] in LDS: 8 broadcast
// ds_read_b128 (same-address => no bank conflicts, ~1 bank-cycle each),
// 8 accumulators => fdot2 dep chains of length 4.
static __device__ __forceinline__ float dot64(const _Float16* a_sh,
                                              const half2v (&th)[32]) {
    const uint4* pa = (const uint4*)a_sh;
    uint4 q0 = pa[0], q1 = pa[1], q2 = pa[2], q3 = pa[3];
    uint4 q4 = pa[4], q5 = pa[5], q6 = pa[6], q7 = pa[7];
    float a0 = 0.f, a1 = 0.f, a2 = 0.f, a3 = 0.f;
    float a4 = 0.f, a5 = 0.f, a6 = 0.f, a7 = 0.f;
    a0 = fdot2(bch(q0.x), th[ 0], a0);  a1 = fdot2(bch(q0.y), th[ 1], a1);
    a2 = fdot2(bch(q0.z), th[ 2], a2);  a3 = fdot2(bch(q0.w), th[ 3], a3);
    a4 = fdot2(bch(q1.x), th[ 4], a4);  a5 = fdot2(bch(q1.y), th[ 5], a5);
    a6 = fdot2(bch(q1.z), th[ 6], a6);  a7 = fdot2(bch(q1.w), th[ 7], a7);
    a0 = fdot2(bch(q2.x), th[ 8], a0);  a1 = fdot2(bch(q2.y), th[ 9], a1);
    a2 = fdot2(bch(q2.z), th[10], a2);  a3 = fdot2(bch(q2.w), th[11], a3);
    a4 = fdot2(bch(q3.x), th[12], a4);  a5 = fdot2(bch(q3.y), th[13], a5);
    a6 = fdot2(bch(q3.z), th[14], a6);  a7 = fdot2(bch(q3.w), th[15], a7);
    a0 = fdot2(bch(q4.x), th[16], a0);  a1 = fdot2(bch(q4.y), th[17], a1);
    a2 = fdot2(bch(q4.z), th[18], a2);  a3 = fdot2(bch(q4.w), th[19], a3);
    a4 = fdot2(bch(q5.x), th[20], a4);  a5 = fdot2(bch(q5.y), th[21], a5);
    a6 = fdot2(bch(q5.z), th[22], a6);  a7 = fdot2(bch(q5.w), th[23], a7);
    a0 = fdot2(bch(q6.x), th[24], a0);  a1 = fdot2(bch(q6.y), th[25], a1);
    a2 = fdot2(bch(q6.z), th[26], a2);  a3 = fdot2(bch(q6.w), th[27], a3);
    a4 = fdot2(bch(q7.x), th[28], a4);  a5 = fdot2(bch(q7.y), th[29], a5);
    a6 = fdot2(bch(q7.z), th[30], a6);  a7 = fdot2(bch(q7.w), th[31], a7);
    return ((a0 + a1) + (a2 + a3)) + ((a4 + a5) + (a6 + a7));
}

// B=256, T=1024, K=64. One wave per batch; lane j owns state j.
// Exp-domain forward recursion: A_t = (Texp^T A_{t-1}) .* exp(em_t)*2^-7;
// exact pow2 re-centering each 8-step chunk folds scale into L.
// No barriers in the loop (single wave => DS pipe is in-order).
// y row + transition matrix live in LDS (no SMEM loads in the loop =>
// no coarse lgkmcnt(0) drains against the DS pipe). waves_per_eu(1,1):
// we launch exactly 1 wave/CU, so let the allocator use the full RF
// instead of spilling th[] to scratch (R3/R4 pinned VGPR_Count=48).
__global__
__attribute__((amdgpu_flat_work_group_size(64, 64), amdgpu_waves_per_eu(1, 1)))
void crf_fwd(
    const int*   __restrict__ yg,   // (B,T) int32
    const float* __restrict__ em,   // (B,T,K) fp32
    const float* __restrict__ tr,   // (K,K) fp32
    float*       __restrict__ out)  // scalar
{
    constexpr int T = 1024, K = 64;
    const int b = blockIdx.x;
    const int j = threadIdx.x;

    __shared__ float    tr_lds[K * K];                       // 16 KB
    __shared__ int      y_lds[T];                            // 4 KB
    __shared__ _Float16 a_sh[K] __attribute__((aligned(16)));

    // ---- one-time staging ----
    for (int k = j; k < K * K; k += K) tr_lds[k] = tr[k];
    const int ybase = b * T;
    for (int k = j; k < T; k += K) y_lds[k] = yg[ybase + k];
    __syncthreads();   // only barrier in the kernel

    // lane j holds column j of exp(trans) packed as 32 half2 (32 VGPRs)
    half2v th[32];
#pragma unroll
    for (int i = 0; i < 32; ++i) {
        half2v h;
        h.x = (_Float16)exp2f(tr_lds[(2 * i) * K + j] * LOG2E);
        h.y = (_Float16)exp2f(tr_lds[(2 * i + 1) * K + j] * LOG2E);
        th[i] = h;
    }

    const float* emb = em + (size_t)b * T * K;

    // ---- t = 0: alpha0 = emissions[:,0,:], centered on its max ----
    const float e0 = emb[j];
    float M0 = e0;
#pragma unroll
    for (int o = 32; o > 0; o >>= 1) M0 = fmaxf(M0, __shfl_xor(M0, o, 64));
    float a = exp2f((e0 - M0) * LOG2E);   // max = 1
    float L = M0;                         // alpha_j = L + log(a_j)

    const int y0 = y_lds[0];
    float e_part = (y0 != 0 && j == y0) ? e0 : 0.0f;
    float t_part = 0.0f;
    int   nupd   = 0;
    int   yprev  = y0;

    a_sh[j] = (_Float16)a;

    // ---- emission prefetch for t = 1..8 (only register buffer) ----
    float ld[8];
#pragma unroll
    for (int u = 0; u < 8; ++u) ld[u] = emb[(1 + u) * K + j];

    // ---- main loop: 127 chunks of 8 steps (t = 1..1016) ----
    for (int tb = 1; tb <= T - 15; tb += 8) {
        // -- chunk top (overlaps first dot's LDS latency) --
        float exc[8], raw[8];
#pragma unroll
        for (int u = 0; u < 8; ++u) {
            raw[u] = ld[u];
            exc[u] = exp2f(ld[u] * LOG2E - 7.0f);   // exp(em) * 2^-7 folded
        }
#pragma unroll
        for (int u = 0; u < 8; ++u) {               // prefetch chunk+1
            int tn = tb + 8 + u; tn = (tn > T - 1) ? (T - 1) : tn;
            ld[u] = emb[tn * K + j];
        }
        unsigned upm = 0;
        {
            int yp = yprev;
#pragma unroll
            for (int u = 0; u < 8; ++u) {
                const int yt = y_lds[tb + u];        // broadcast DS read
                const bool up = (yt != 0);
                const float tv = tr_lds[yp * K + yt];// broadcast DS read
                upm    |= up ? (1u << u) : 0u;
                t_part += up ? tv : 0.0f;
                nupd   += up ? 1 : 0;
                e_part += (up && j == yt) ? raw[u] : 0.0f;
                yp = yt;
            }
            yprev = yp;
        }

        // -- 8 serial recursion steps (the critical path) --
#pragma unroll
        for (int u = 0; u < 8; ++u) {
            const float s  = dot64(a_sh, th);
            const float an = s * exc[u];
            a = ((upm >> u) & 1u) ? an : a;
            a_sh[j] = (_Float16)fminf(a, 60000.0f);  // clamp: no f16 inf
        }

        // -- chunk-end re-centering by exact power of two (wave-uniform) --
        unsigned ab = (unsigned)__builtin_amdgcn_readlane((int)__float_as_uint(a), 0);
        int ef = (int)((ab >> 23) & 0xFF);
        if (ef > 0 && ef < 255 && ef != 127) {
            const int E = ef - 127;
            const float sc = __uint_as_float((unsigned)(127 - E) << 23); // 2^-E
            a *= sc;
            L += (float)E * LN2;
            a_sh[j] = (_Float16)fminf(a, 60000.0f);
        }
    }

    // ---- tail: t = 1017..1023 (ld[0..6] hold them) ----
#pragma unroll
    for (int u = 0; u < 7; ++u) {
        const int t  = 1017 + u;
        const int yt = y_lds[t];
        const bool up = (yt != 0);
        const float tv = tr_lds[yprev * K + yt];
        const float ex = exp2f(ld[u] * LOG2E - 7.0f);
        const float s  = dot64(a_sh, th);
        const float an = s * ex;
        t_part += up ? tv : 0.0f;
        nupd   += up ? 1 : 0;
        e_part += (up && j == yt) ? ld[u] : 0.0f;
        a = up ? an : a;
        a_sh[j] = (_Float16)fminf(a, 60000.0f);
        yprev = yt;
    }

    L += 7.0f * LN2 * (float)nupd;   // fold the per-update 2^-7 scales

    // ---- finalize: log_z = L + log(sum_j a_j) ----
    float asum = a, esum = e_part;
#pragma unroll
    for (int o = 32; o > 0; o >>= 1) {
        asum += __shfl_xor(asum, o, 64);
        esum += __shfl_xor(esum, o, 64);
    }
    const float logz = L + __log2f(asum) * LN2;

    if (j == 0) {
        const float ll = esum + t_part - logz;
        atomicAdd(out, ll * (-1.0f / 256.0f));  // -mean over B
    }
}

extern "C" void kernel_launch(void* const* d_in, const int* in_sizes, int n_in,
                              void* d_out, int out_size, void* d_ws, size_t ws_size,
                              hipStream_t stream) {
    const int*   y  = (const int*)d_in[0];
    const float* em = (const float*)d_in[1];
    const float* tr = (const float*)d_in[2];
    float* out = (float*)d_out;

    hipMemsetAsync(out, 0, sizeof(float), stream);
    crf_fwd<<<dim3(256), dim3(64), 0, stream>>>(y, em, tr, out);
}

// Round 6
// 244.586 us; speedup vs baseline: 1.4987x; 1.1800x over previous
//
#include <hip/hip_runtime.h>

#define LOG2E 1.44269504088896340736f
#define LN2   0.69314718055994530942f

typedef short bf8 __attribute__((ext_vector_type(8)));   // 8 bf16 (A/B frag)
typedef float f4  __attribute__((ext_vector_type(4)));   // 4 f32  (C/D frag)

static __device__ __forceinline__ unsigned short f2bf_rne(float f) {
    unsigned u = __float_as_uint(f);
    u += 0x7FFFu + ((u >> 16) & 1u);
    return (unsigned short)(u >> 16);
}
// pack two f32 -> two bf16 (truncation; bias ~ -2 on logZ over 1023 steps, OK)
static __device__ __forceinline__ unsigned pack_bf_trunc(float lo, float hi) {
    return __builtin_amdgcn_perm(__float_as_uint(hi), __float_as_uint(lo), 0x07060302u);
}

// ============================================================================
// Kernel 1: per-(batch, 64-step chunk) operator product.
//   Op_t = mask_t ? D_t * M^T : I,  D_t = diag(exp(em_t) * 2^-7), M = exp(tr)
//   P_c  = Op_{t0+63} ... Op_{t0}   (64x64), stored bf16 to workspace as P^T
//   (row j of the dump = column j of P_c, ready for the combine matvec).
// One wave per chunk; 16 chunks x 256 batches = 4096 blocks -> scan is
// throughput-bound on MFMA+VALU instead of latency-bound on a serial chain.
// ============================================================================
__global__ __attribute__((amdgpu_flat_work_group_size(64, 64), amdgpu_waves_per_eu(1, 4)))
void crf_scan(const int* __restrict__ yg, const float* __restrict__ em,
              const float* __restrict__ tr, unsigned short* __restrict__ Pg)
{
    constexpr int T = 1024, STR = 72;   // LDS row stride 72 bf16: 16B-aligned rows, <=2-way banks
    const int c = blockIdx.x, b = blockIdx.y;
    const int lane = threadIdx.x, nl = lane & 15, q = lane >> 4;

    __shared__ __align__(16) unsigned short p_sh[64 * STR];  // P^T: p_sh[n*STR+k] = P[k][n]
    __shared__ float d_sh[64];

    // ---- P = I (each lane owns row 'lane'; single wave => DS pipe in-order,
    //      no barrier needed anywhere in this kernel) ----
    #pragma unroll
    for (int r = 0; r < 9; ++r) {
        uint4 z; z.x = z.y = z.z = z.w = 0u;
        *(uint4*)&p_sh[lane * STR + r * 8] = z;
    }
    p_sh[lane * STR + lane] = 0x3F80;   // bf16 1.0

    // ---- A-fragments of M^T (constant): A[m][k]=exp(tr[k][m]),
    //      layout m=lane&15, k=8*(lane>>4)+j  [HW-verified m120] ----
    bf8 afr[4][2];
    #pragma unroll
    for (int mt = 0; mt < 4; ++mt)
        #pragma unroll
        for (int kt = 0; kt < 2; ++kt) {
            bf8 v;
            #pragma unroll
            for (int j = 0; j < 8; ++j) {
                const int k = 32 * kt + 8 * q + j, m = 16 * mt + nl;
                v[j] = (short)f2bf_rne(exp2f(tr[k * 64 + m] * LOG2E));
            }
            afr[mt][kt] = v;
        }

    const int t0 = 1 + 64 * c;
    const int nsteps = (c == 15) ? 63 : 64;
    const float* emb = em + (size_t)b * T * 64;

    int tl = t0 + lane; if (tl > T - 1) tl = T - 1;
    const int yvl = yg[b * T + tl];
    const unsigned long long msk = __ballot(lane < nsteps && yvl != 0);

    float ldc = emb[t0 * 64 + lane];                  // emission prefetch (1 deep)
    for (int s = 0; s < nsteps; ++s) {
        int tn = t0 + s + 1; if (tn > T - 1) tn = T - 1;
        const float ldn = emb[tn * 64 + lane];
        if ((msk >> s) & 1ull) {                      // wave-uniform
            d_sh[lane] = exp2f(ldc * LOG2E - 7.0f);   // d[state=lane]
            // B-fragments of current P: B[k][n], n=lane&15, k=8*(lane>>4)+j
            bf8 bfr[2][4];
            #pragma unroll
            for (int kt = 0; kt < 2; ++kt)
                #pragma unroll
                for (int nt = 0; nt < 4; ++nt)
                    bfr[kt][nt] = *(const bf8*)&p_sh[(16 * nt + nl) * STR + 32 * kt + 8 * q];
            // d for my C rows: row = 16*mt + 4*q + r  (broadcast reads, no conflicts)
            float d16[4][4];
            #pragma unroll
            for (int mt = 0; mt < 4; ++mt)
                #pragma unroll
                for (int r = 0; r < 4; ++r)
                    d16[mt][r] = d_sh[16 * mt + 4 * q + r];
            // C = M^T * P (f32), scale rows by d, truncate->bf16, write back P^T
            #pragma unroll
            for (int mt = 0; mt < 4; ++mt)
                #pragma unroll
                for (int nt = 0; nt < 4; ++nt) {
                    f4 acc = __builtin_amdgcn_mfma_f32_16x16x32_bf16(
                                 afr[mt][0], bfr[0][nt], (f4)(0.0f), 0, 0, 0);
                    acc = __builtin_amdgcn_mfma_f32_16x16x32_bf16(
                                 afr[mt][1], bfr[1][nt], acc, 0, 0, 0);
                    const unsigned p0 = pack_bf_trunc(acc[0] * d16[mt][0], acc[1] * d16[mt][1]);
                    const unsigned p1 = pack_bf_trunc(acc[2] * d16[mt][2], acc[3] * d16[mt][3]);
                    uint2 w; w.x = p0; w.y = p1;     // rows 16mt+4q+0..3, col n
                    *(uint2*)&p_sh[(16 * nt + nl) * STR + 16 * mt + 4 * q] = w;
                }
        }
        ldc = ldn;
    }

    // ---- dump P^T rows (drop pad): Pg[(b*16+c)*4096 + j*64 + i] = P_c[i][j] ----
    unsigned short* pg = Pg + ((size_t)(b * 16 + c) << 12);
    #pragma unroll
    for (int r = 0; r < 8; ++r)
        *(uint4*)(pg + lane * 64 + r * 8) = *(const uint4*)&p_sh[lane * STR + r * 8];
}

// ============================================================================
// Kernel 2: per-batch combine — v = P_15 ... P_0 * exp(e0 - M0), plus the
// gather scores, logZ, and the final -mean accumulation. 256 waves.
// ============================================================================
__global__ __attribute__((amdgpu_flat_work_group_size(64, 64), amdgpu_waves_per_eu(1, 1)))
void crf_combine(const int* __restrict__ yg, const float* __restrict__ em,
                 const float* __restrict__ tr, const unsigned short* __restrict__ Pg,
                 float* __restrict__ out)
{
    constexpr int T = 1024;
    const int b = blockIdx.x, j = threadIdx.x;
    __shared__ __align__(16) float v_sh[64];

    const float e0 = em[(size_t)b * T * 64 + j];
    float M0 = e0;
    #pragma unroll
    for (int o = 32; o > 0; o >>= 1) M0 = fmaxf(M0, __shfl_xor(M0, o, 64));
    float v = exp2f((e0 - M0) * LOG2E);
    float L = M0;

    // ---- scores + unmasked-step count (lane-strided over t) ----
    const int* yb = yg + b * T;
    int cnt = 0; float ep = 0.f, tp = 0.f;
    for (int t = 1 + j; t < T; t += 64) {
        const int yt = yb[t];
        if (yt != 0) {
            ++cnt;
            tp += tr[yb[t - 1] * 64 + yt];
            ep += em[((size_t)b * T + t) * 64 + yt];
        }
    }
    if (j == 0) {
        const int y0 = yb[0];
        if (y0 != 0) ep += em[(size_t)b * T * 64 + y0];
    }

    // ---- apply the 16 chunk operators ----
    const unsigned short* pgb = Pg + ((size_t)(b * 16) << 12);
    for (int c = 0; c < 16; ++c) {
        v_sh[j] = v;                                   // single wave: in-order DS
        const unsigned short* row = pgb + ((size_t)c << 12) + j * 64;  // column j of P_c
        float s0 = 0.f, s1 = 0.f, s2 = 0.f, s3 = 0.f;
        #pragma unroll
        for (int r = 0; r < 8; ++r) {
            const uint4 qq = *(const uint4*)(row + r * 8);
            const float* vp = &v_sh[r * 8];
            s0 = fmaf(__uint_as_float(qq.x << 16),         vp[0], s0);
            s1 = fmaf(__uint_as_float(qq.x & 0xFFFF0000u), vp[1], s1);
            s2 = fmaf(__uint_as_float(qq.y << 16),         vp[2], s2);
            s3 = fmaf(__uint_as_float(qq.y & 0xFFFF0000u), vp[3], s3);
            s0 = fmaf(__uint_as_float(qq.z << 16),         vp[4], s0);
            s1 = fmaf(__uint_as_float(qq.z & 0xFFFF0000u), vp[5], s1);
            s2 = fmaf(__uint_as_float(qq.w << 16),         vp[6], s2);
            s3 = fmaf(__uint_as_float(qq.w & 0xFFFF0000u), vp[7], s3);
        }
        float s = (s0 + s1) + (s2 + s3);
        // exact-pow2 re-centering (wave-uniform), fold into L
        const unsigned sb = (unsigned)__builtin_amdgcn_readlane((int)__float_as_uint(s), 0);
        const int ef = (int)((sb >> 23) & 0xFF);
        if (ef > 0 && ef < 255 && ef != 127) {
            const int E = ef - 127;
            s *= __uint_as_float((unsigned)(127 - E) << 23);
            L += (float)E * LN2;
        }
        v = s;
    }

    // ---- reduce & finalize ----
    float vs = v, eps = ep, tps = tp; int cs = cnt;
    #pragma unroll
    for (int o = 32; o > 0; o >>= 1) {
        vs  += __shfl_xor(vs, o, 64);
        eps += __shfl_xor(eps, o, 64);
        tps += __shfl_xor(tps, o, 64);
        cs  += __shfl_xor(cs, o, 64);
    }
    if (j == 0) {
        const float logz = L + 7.0f * LN2 * (float)cs + __log2f(vs) * LN2;
        const float ll = eps + tps - logz;
        atomicAdd(out, ll * (-1.0f / 256.0f));
    }
}

extern "C" void kernel_launch(void* const* d_in, const int* in_sizes, int n_in,
                              void* d_out, int out_size, void* d_ws, size_t ws_size,
                              hipStream_t stream) {
    const int*   y  = (const int*)d_in[0];
    const float* em = (const float*)d_in[1];
    const float* tr = (const float*)d_in[2];
    float* out = (float*)d_out;
    unsigned short* Pg = (unsigned short*)d_ws;   // needs 256*16*4096*2 = 32 MB

    hipMemsetAsync(out, 0, sizeof(float), stream);
    crf_scan<<<dim3(16, 256), dim3(64), 0, stream>>>(y, em, tr, Pg);
    crf_combine<<<dim3(256), dim3(64), 0, stream>>>(y, em, tr, Pg, out);
}